// Round 1
// baseline (556.981 us; speedup 1.0000x reference)
//
#include <hip/hip_runtime.h>
#include <hip/hip_bf16.h>

// Problem constants (from reference): N_IMG=8192, N_TXT=8192, D=1024, H=1024
#define NI 8192
#define NT 8192
#define DD 1024
#define HH 1024

using bf16x8 = __attribute__((ext_vector_type(8))) __bf16;
using bf16x4 = __attribute__((ext_vector_type(4))) __bf16;
using f32x4  = __attribute__((ext_vector_type(4))) float;

// ---------------------------------------------------------------------------
// fp32 -> bf16 conversion (vectorized)
// ---------------------------------------------------------------------------
__global__ void cvt_kernel(const float* __restrict__ src, __bf16* __restrict__ dst, int n) {
    int i = (blockIdx.x * 256 + threadIdx.x) * 4;
    if (i < n) {
        float4 v = *(const float4*)(src + i);
        bf16x4 o;
        o[0] = (__bf16)v.x; o[1] = (__bf16)v.y; o[2] = (__bf16)v.z; o[3] = (__bf16)v.w;
        *(bf16x4*)(dst + i) = o;
    }
}

// ---------------------------------------------------------------------------
// NT GEMM: C[m,n] = epi( sum_k A[m,k] * B[n,k] )
// A: [M x K] bf16 row-major, B: [N x K] bf16 row-major.
// 128x128 tile, BK=64, 256 threads (4 waves, 2x2), mfma 16x16x32 bf16.
// Requires M,N % 128 == 0 and K % 64 == 0 (true for all shapes here).
// ---------------------------------------------------------------------------
enum { EPI_BF16 = 0, EPI_EXP_BF16 = 1, EPI_DIV_F32 = 2 };

__device__ __forceinline__ void async_copy16(const __bf16* g, __bf16* l) {
    __builtin_amdgcn_global_load_lds(
        (const __attribute__((address_space(1))) void*)g,
        (__attribute__((address_space(3))) void*)l,
        16, 0, 0);
}

template <int EPI>
__launch_bounds__(256, 2)
__global__ void gemm_bt(const __bf16* __restrict__ A, const __bf16* __restrict__ B,
                        void* __restrict__ Cout, const float* __restrict__ lvec,
                        int M, int N, int K, float scale)
{
    __shared__ __bf16 As[128 * 64];
    __shared__ __bf16 Bs[128 * 64];

    const int t    = threadIdx.x;
    const int lane = t & 63;
    const int wave = t >> 6;       // 0..3
    const int wm   = wave >> 1;    // 0..1
    const int wn   = wave & 1;     // 0..1
    const int bm   = blockIdx.y * 128;
    const int bn   = blockIdx.x * 128;

    f32x4 acc[4][4];
#pragma unroll
    for (int i = 0; i < 4; ++i)
#pragma unroll
        for (int j = 0; j < 4; ++j) acc[i][j] = (f32x4){0.f, 0.f, 0.f, 0.f};

    const int q  = lane >> 4;   // 0..3
    const int ml = lane & 15;   // 0..15

    for (int kk = 0; kk < K; kk += 64) {
        // --- stage A-tile [128 x 64] and B-tile [128 x 64] via global_load_lds(16B)
#pragma unroll
        for (int it = 0; it < 4; ++it) {
            int e = (it * 256 + t) * 8;     // element index in tile (row-major [128][64])
            int r = e >> 6, c = e & 63;
            async_copy16(A + (size_t)(bm + r) * K + kk + c, As + e);
        }
#pragma unroll
        for (int it = 0; it < 4; ++it) {
            int e = (it * 256 + t) * 8;
            int r = e >> 6, c = e & 63;
            async_copy16(B + (size_t)(bn + r) * K + kk + c, Bs + e);
        }
        __syncthreads();   // drains vmcnt before barrier (compiler-inserted)

#pragma unroll
        for (int ks = 0; ks < 64; ks += 32) {
            bf16x8 af[4], bfv[4];
#pragma unroll
            for (int rf = 0; rf < 4; ++rf)
                af[rf] = *(const bf16x8*)(As + (wm * 64 + rf * 16 + ml) * 64 + ks + q * 8);
#pragma unroll
            for (int cf = 0; cf < 4; ++cf)
                bfv[cf] = *(const bf16x8*)(Bs + (wn * 64 + cf * 16 + ml) * 64 + ks + q * 8);
#pragma unroll
            for (int rf = 0; rf < 4; ++rf)
#pragma unroll
                for (int cf = 0; cf < 4; ++cf)
                    acc[rf][cf] = __builtin_amdgcn_mfma_f32_16x16x32_bf16(
                        af[rf], bfv[cf], acc[rf][cf], 0, 0, 0);
        }
        __syncthreads();
    }

    // --- epilogue: C/D layout col = lane&15, row = (lane>>4)*4 + reg (m89-verified)
#pragma unroll
    for (int rf = 0; rf < 4; ++rf) {
#pragma unroll
        for (int i = 0; i < 4; ++i) {
            int row = bm + wm * 64 + rf * 16 + q * 4 + i;
            float rl = 0.f;
            if (EPI == EPI_DIV_F32) rl = 1.0f / lvec[row];
#pragma unroll
            for (int cf = 0; cf < 4; ++cf) {
                int col = bn + wn * 64 + cf * 16 + ml;
                float v = acc[rf][cf][i];
                if (EPI == EPI_BF16) {
                    ((__bf16*)Cout)[(size_t)row * N + col] = (__bf16)v;
                } else if (EPI == EPI_EXP_BF16) {
                    ((__bf16*)Cout)[(size_t)row * N + col] = (__bf16)__expf(v * scale);
                } else {
                    ((float*)Cout)[(size_t)row * N + col] = v * rl;
                }
            }
        }
    }
}

// ---------------------------------------------------------------------------
// Row-sum of bf16 matrix P [rows x N] -> l[rows] (fp32)
// ---------------------------------------------------------------------------
__global__ void rowsum_kernel(const __bf16* __restrict__ P, float* __restrict__ l, int N) {
    int row = blockIdx.x;
    const __bf16* p = P + (size_t)row * N;
    float s = 0.f;
    for (int i = threadIdx.x * 8; i < N; i += 256 * 8) {
        bf16x8 v = *(const bf16x8*)(p + i);
#pragma unroll
        for (int j = 0; j < 8; ++j) s += (float)v[j];
    }
#pragma unroll
    for (int off = 32; off > 0; off >>= 1) s += __shfl_down(s, off);
    __shared__ float red[4];
    if ((threadIdx.x & 63) == 0) red[threadIdx.x >> 6] = s;
    __syncthreads();
    if (threadIdx.x == 0) l[row] = red[0] + red[1] + red[2] + red[3];
}

// ---------------------------------------------------------------------------
extern "C" void kernel_launch(void* const* d_in, const int* in_sizes, int n_in,
                              void* d_out, int out_size, void* d_ws, size_t ws_size,
                              hipStream_t stream) {
    const float* img  = (const float*)d_in[0];  // [NI x DD]
    const float* text = (const float*)d_in[1];  // [NT x DD]
    const float* WQ   = (const float*)d_in[2];  // [HH x DD]
    const float* WK   = (const float*)d_in[3];  // [HH x DD]
    const float* WV   = (const float*)d_in[4];  // [DD x DD]

    // workspace layout (bf16 buffers)
    char* ws = (char*)d_ws;
    size_t off = 0;
    auto alloc = [&](size_t bytes) -> void* {
        void* p = ws + off;
        off += (bytes + 255) & ~(size_t)255;
        return p;
    };
    __bf16* imgb  = (__bf16*)alloc((size_t)NI * DD * 2);
    __bf16* textb = (__bf16*)alloc((size_t)NT * DD * 2);
    __bf16* wqb   = (__bf16*)alloc((size_t)HH * DD * 2);
    __bf16* wkb   = (__bf16*)alloc((size_t)HH * DD * 2);
    __bf16* wvb   = (__bf16*)alloc((size_t)DD * DD * 2);
    __bf16* Qb    = (__bf16*)alloc((size_t)NI * HH * 2);
    __bf16* Kb    = (__bf16*)alloc((size_t)NT * HH * 2);
    __bf16* Vtb   = (__bf16*)alloc((size_t)DD * NT * 2);   // V transposed: [DD x NT]
    __bf16* Pb    = (__bf16*)alloc((size_t)NI * NT * 2);   // 128 MiB
    float*  lv    = (float*)alloc((size_t)NI * 4);
    if (off > ws_size) return;  // workspace too small — fail loudly rather than corrupt

    const float scale = 0.03125f;  // 1/sqrt(1024)

    // 1) convert inputs to bf16
    auto cvt = [&](const float* s, __bf16* d, int n) {
        cvt_kernel<<<dim3((n / 4 + 255) / 256), dim3(256), 0, stream>>>(s, d, n);
    };
    cvt(img,  imgb,  NI * DD);
    cvt(text, textb, NT * DD);
    cvt(WQ,   wqb,   HH * DD);
    cvt(WK,   wkb,   HH * DD);
    cvt(WV,   wvb,   DD * DD);

    // 2) Q = img @ WQ^T  [NI x HH]
    gemm_bt<EPI_BF16><<<dim3(HH / 128, NI / 128), dim3(256), 0, stream>>>(
        imgb, wqb, Qb, nullptr, NI, HH, DD, 1.f);
    // 3) K = text @ WK^T [NT x HH]
    gemm_bt<EPI_BF16><<<dim3(HH / 128, NT / 128), dim3(256), 0, stream>>>(
        textb, wkb, Kb, nullptr, NT, HH, DD, 1.f);
    // 4) Vt = WV @ text^T [DD x NT]  (Vt[d,j] = sum_k WV[d,k] text[j,k] = V[j,d])
    gemm_bt<EPI_BF16><<<dim3(NT / 128, DD / 128), dim3(256), 0, stream>>>(
        wvb, textb, Vtb, nullptr, DD, NT, DD, 1.f);
    // 5) P = exp(scale * Q @ K^T) [NI x NT], bf16
    gemm_bt<EPI_EXP_BF16><<<dim3(NT / 128, NI / 128), dim3(256), 0, stream>>>(
        Qb, Kb, Pb, nullptr, NI, NT, HH, scale);
    // 6) l = rowsum(P)
    rowsum_kernel<<<dim3(NI), dim3(256), 0, stream>>>(Pb, lv, NT);
    // 7) O = (P @ Vt^T) / l  [NI x DD], fp32 to d_out
    gemm_bt<EPI_DIV_F32><<<dim3(DD / 128, NI / 128), dim3(256), 0, stream>>>(
        Pb, Vtb, d_out, lv, NI, DD, NT, 1.f);
}

// Round 2
// 534.392 us; speedup vs baseline: 1.0423x; 1.0423x over previous
//
#include <hip/hip_runtime.h>
#include <hip/hip_bf16.h>

// Problem constants: N_IMG=8192, N_TXT=8192, D=1024, H=1024
#define NI 8192
#define NT 8192
#define DD 1024
#define HH 1024

using bf16x8 = __attribute__((ext_vector_type(8))) __bf16;
using bf16x4 = __attribute__((ext_vector_type(4))) __bf16;
using f32x4  = __attribute__((ext_vector_type(4))) float;

// ---------------------------------------------------------------------------
// fp32 -> bf16 conversion (vectorized)
// ---------------------------------------------------------------------------
__global__ void cvt_kernel(const float* __restrict__ src, __bf16* __restrict__ dst, int n) {
    int i = (blockIdx.x * 256 + threadIdx.x) * 4;
    if (i < n) {
        float4 v = *(const float4*)(src + i);
        bf16x4 o;
        o[0] = (__bf16)v.x; o[1] = (__bf16)v.y; o[2] = (__bf16)v.z; o[3] = (__bf16)v.w;
        *(bf16x4*)(dst + i) = o;
    }
}

// ---------------------------------------------------------------------------
// NT GEMM: C[m,n] = epi( sum_k A[m,k] * B[n,k] )
// 128x128 tile, BK=64, 256 threads (4 waves, 2x2), mfma 16x16x32 bf16.
// LDS tiles use XOR swizzle: 16B group g of row r stored at group g^(r&7).
// The swizzle is applied to the GLOBAL source column during global_load_lds
// staging (LDS dest must stay wave-uniform-base + lane*16), and to the LDS
// address at fragment-read time. Spreads b128 reads over all 32 banks
// (8 lanes/bank-group instead of 16 on a 16-bank subset).
// ---------------------------------------------------------------------------
enum { EPI_BF16 = 0, EPI_EXP_ROWSUM = 1, EPI_F32 = 2 };

__device__ __forceinline__ void async_copy16(const __bf16* g, __bf16* l) {
    __builtin_amdgcn_global_load_lds(
        (const __attribute__((address_space(1))) void*)g,
        (__attribute__((address_space(3))) void*)l,
        16, 0, 0);
}

template <int EPI>
__launch_bounds__(256, 4)   // min 4 waves/EU -> regalloc <=128 VGPR (have ~76)
__global__ void gemm_bt(const __bf16* __restrict__ A, const __bf16* __restrict__ B,
                        void* __restrict__ Cout, float* __restrict__ lvec,
                        int M, int N, int K, int ksplit, float scale)
{
    __shared__ __bf16 As[128 * 64];
    __shared__ __bf16 Bs[128 * 64];

    const int t    = threadIdx.x;
    const int lane = t & 63;
    const int wave = t >> 6;
    const int wm   = wave >> 1;
    const int wn   = wave & 1;
    const int bm   = blockIdx.y * 128;
    const int bn   = blockIdx.x * 128;
    const int k0   = blockIdx.z * ksplit;

    f32x4 acc[4][4];
#pragma unroll
    for (int i = 0; i < 4; ++i)
#pragma unroll
        for (int j = 0; j < 4; ++j) acc[i][j] = (f32x4){0.f, 0.f, 0.f, 0.f};

    const int q  = lane >> 4;   // 0..3
    const int ml = lane & 15;   // 0..15
    const int sw = ml & 7;      // row-derived swizzle (row%8 == ml%8 for our frags)

    for (int kk = k0; kk < k0 + ksplit; kk += 64) {
        // stage A/B tiles [128 x 64]; swizzle source column by dest row
#pragma unroll
        for (int it = 0; it < 4; ++it) {
            int idx = it * 256 + t;                 // 16B-group index in tile
            int r   = idx >> 3;                     // dest row
            int c   = ((idx & 7) ^ (r & 7)) << 3;   // swizzled source column (elems)
            async_copy16(A + (size_t)(bm + r) * K + kk + c, As + idx * 8);
        }
#pragma unroll
        for (int it = 0; it < 4; ++it) {
            int idx = it * 256 + t;
            int r   = idx >> 3;
            int c   = ((idx & 7) ^ (r & 7)) << 3;
            async_copy16(B + (size_t)(bn + r) * K + kk + c, Bs + idx * 8);
        }
        __syncthreads();

#pragma unroll
        for (int ks = 0; ks < 64; ks += 32) {
            const int gb = ks >> 3;
            bf16x8 af[4], bfv[4];
#pragma unroll
            for (int rf = 0; rf < 4; ++rf)
                af[rf] = *(const bf16x8*)(As + (wm * 64 + rf * 16 + ml) * 64 +
                                          (((gb + q) ^ sw) << 3));
#pragma unroll
            for (int cf = 0; cf < 4; ++cf)
                bfv[cf] = *(const bf16x8*)(Bs + (wn * 64 + cf * 16 + ml) * 64 +
                                           (((gb + q) ^ sw) << 3));
#pragma unroll
            for (int rf = 0; rf < 4; ++rf)
#pragma unroll
                for (int cf = 0; cf < 4; ++cf)
                    acc[rf][cf] = __builtin_amdgcn_mfma_f32_16x16x32_bf16(
                        af[rf], bfv[cf], acc[rf][cf], 0, 0, 0);
        }
        __syncthreads();
    }

    // epilogue: C/D layout col = lane&15, row = (lane>>4)*4 + reg
#pragma unroll
    for (int rf = 0; rf < 4; ++rf) {
#pragma unroll
        for (int i = 0; i < 4; ++i) {
            int row = bm + wm * 64 + rf * 16 + q * 4 + i;
            if (EPI == EPI_BF16) {
#pragma unroll
                for (int cf = 0; cf < 4; ++cf) {
                    int col = bn + wn * 64 + cf * 16 + ml;
                    ((__bf16*)Cout)[(size_t)row * N + col] = (__bf16)acc[rf][cf][i];
                }
            } else if (EPI == EPI_EXP_ROWSUM) {
                float s = 0.f;
#pragma unroll
                for (int cf = 0; cf < 4; ++cf) {
                    int col = bn + wn * 64 + cf * 16 + ml;
                    __bf16 pv = (__bf16)__expf(acc[rf][cf][i] * scale);
                    ((__bf16*)Cout)[(size_t)row * N + col] = pv;
                    s += (float)pv;   // sum the bf16-rounded value: matches numerator
                }
                // reduce across the 16 lanes of this quad (same row)
                s += __shfl_xor(s, 1);
                s += __shfl_xor(s, 2);
                s += __shfl_xor(s, 4);
                s += __shfl_xor(s, 8);
                if (ml == 0) atomicAdd(lvec + row, s);
            } else {  // EPI_F32: split-K partial
                float* outp = (float*)Cout + (size_t)blockIdx.z * M * N;
#pragma unroll
                for (int cf = 0; cf < 4; ++cf) {
                    int col = bn + wn * 64 + cf * 16 + ml;
                    outp[(size_t)row * N + col] = acc[rf][cf][i];
                }
            }
        }
    }
}

// ---------------------------------------------------------------------------
// combine split-K partials and divide by row sum:  out = (p0+p1)/l[row]
// ---------------------------------------------------------------------------
__global__ void combine_kernel(const float* __restrict__ p0, const float* __restrict__ p1,
                               const float* __restrict__ l, float* __restrict__ out) {
    int i4  = (blockIdx.x * 256 + threadIdx.x) * 4;
    int row = i4 >> 10;   // DD = 1024
    float rl = 1.0f / l[row];
    float4 a = *(const float4*)(p0 + i4);
    float4 b = *(const float4*)(p1 + i4);
    float4 o;
    o.x = (a.x + b.x) * rl;
    o.y = (a.y + b.y) * rl;
    o.z = (a.z + b.z) * rl;
    o.w = (a.w + b.w) * rl;
    *(float4*)(out + i4) = o;
}

// ---------------------------------------------------------------------------
extern "C" void kernel_launch(void* const* d_in, const int* in_sizes, int n_in,
                              void* d_out, int out_size, void* d_ws, size_t ws_size,
                              hipStream_t stream) {
    const float* img  = (const float*)d_in[0];
    const float* text = (const float*)d_in[1];
    const float* WQ   = (const float*)d_in[2];
    const float* WK   = (const float*)d_in[3];
    const float* WV   = (const float*)d_in[4];

    char* ws = (char*)d_ws;
    size_t off = 0;
    auto alloc = [&](size_t bytes) -> void* {
        void* p = ws + off;
        off += (bytes + 255) & ~(size_t)255;
        return p;
    };
    // NOTE: imgb/textb/Qb/Kb placed first & contiguous (64 MiB): all four are
    // dead by the time the O-GEMM runs, so its split-K fp32 partials reuse them.
    __bf16* imgb  = (__bf16*)alloc((size_t)NI * DD * 2);   // 16 MiB
    __bf16* textb = (__bf16*)alloc((size_t)NT * DD * 2);   // 16 MiB
    __bf16* Qb    = (__bf16*)alloc((size_t)NI * HH * 2);   // 16 MiB
    __bf16* Kb    = (__bf16*)alloc((size_t)NT * HH * 2);   // 16 MiB
    __bf16* wqb   = (__bf16*)alloc((size_t)HH * DD * 2);
    __bf16* wkb   = (__bf16*)alloc((size_t)HH * DD * 2);
    __bf16* wvb   = (__bf16*)alloc((size_t)DD * DD * 2);
    __bf16* Vtb   = (__bf16*)alloc((size_t)DD * NT * 2);   // V^T [DD x NT]
    __bf16* Pb    = (__bf16*)alloc((size_t)NI * NT * 2);   // 128 MiB
    float*  lv    = (float*)alloc((size_t)NI * 4);
    float*  Opart = (float*)d_ws;                           // 2 x 32 MiB, reuses imgb..Kb
    if (off > ws_size) return;

    const float scale = 0.03125f;  // 1/sqrt(1024)

    auto cvt = [&](const float* s, __bf16* d, int n) {
        cvt_kernel<<<dim3((n / 4 + 255) / 256), dim3(256), 0, stream>>>(s, d, n);
    };
    cvt(img,  imgb,  NI * DD);
    cvt(text, textb, NT * DD);
    cvt(WQ,   wqb,   HH * DD);
    cvt(WK,   wkb,   HH * DD);
    cvt(WV,   wvb,   DD * DD);

    hipMemsetAsync(lv, 0, (size_t)NI * 4, stream);   // rowsum accumulator

    // Q = img @ WQ^T  [NI x HH]
    gemm_bt<EPI_BF16><<<dim3(HH / 128, NI / 128), dim3(256), 0, stream>>>(
        imgb, wqb, Qb, nullptr, NI, HH, DD, DD, 1.f);
    // K = text @ WK^T [NT x HH]
    gemm_bt<EPI_BF16><<<dim3(HH / 128, NT / 128), dim3(256), 0, stream>>>(
        textb, wkb, Kb, nullptr, NT, HH, DD, DD, 1.f);
    // Vt = WV @ text^T [DD x NT]
    gemm_bt<EPI_BF16><<<dim3(NT / 128, DD / 128), dim3(256), 0, stream>>>(
        wvb, textb, Vtb, nullptr, DD, NT, DD, DD, 1.f);
    // P = exp(scale * Q @ K^T) [NI x NT] bf16, rowsums -> lv (atomic)
    gemm_bt<EPI_EXP_ROWSUM><<<dim3(NT / 128, NI / 128), dim3(256), 0, stream>>>(
        Qb, Kb, Pb, lv, NI, NT, HH, HH, scale);
    // O partials: split-K=2 over K=NT (occupancy 2->4 blocks/CU)
    gemm_bt<EPI_F32><<<dim3(DD / 128, NI / 128, 2), dim3(256), 0, stream>>>(
        Pb, Vtb, Opart, nullptr, NI, DD, NT, NT / 2, 1.f);
    // out = (part0 + part1) / l
    combine_kernel<<<dim3(NI * DD / 4 / 256), dim3(256), 0, stream>>>(
        Opart, Opart + (size_t)NI * DD, lv, (float*)d_out);
}

// Round 3
// 475.597 us; speedup vs baseline: 1.1711x; 1.1236x over previous
//
#include <hip/hip_runtime.h>
#include <hip/hip_bf16.h>

// Problem constants: N_IMG=8192, N_TXT=8192, D=1024, H=1024
#define NI 8192
#define NT 8192
#define DD 1024
#define HH 1024

using bf16x8 = __attribute__((ext_vector_type(8))) __bf16;
using bf16x4 = __attribute__((ext_vector_type(4))) __bf16;
using f32x4  = __attribute__((ext_vector_type(4))) float;

// ---------------------------------------------------------------------------
// fused fp32 -> bf16 conversion for all 5 inputs (one dispatch)
// ---------------------------------------------------------------------------
struct CvtArgs {
    const float* src[5];
    __bf16*      dst[5];
    int          blk_end[5];   // exclusive prefix of block counts (n/1024 blocks each)
};

__global__ void cvt_all_kernel(CvtArgs a) {
    int bid = blockIdx.x;
    int r = 0;
    while (bid >= a.blk_end[r]) ++r;                 // wave-uniform, <=5 iters
    int rbid = bid - (r ? a.blk_end[r - 1] : 0);
    int i = (rbid * 256 + threadIdx.x) * 4;          // region sizes are multiples of 1024
    float4 v = *(const float4*)(a.src[r] + i);
    bf16x4 o;
    o[0] = (__bf16)v.x; o[1] = (__bf16)v.y; o[2] = (__bf16)v.z; o[3] = (__bf16)v.w;
    *(bf16x4*)(a.dst[r] + i) = o;
}

// ---------------------------------------------------------------------------
// Shared GEMM core: 128x128 tile, BK=64, 256 threads (4 waves 2x2),
// mfma 16x16x32 bf16, global_load_lds(16B) staging with XOR bank swizzle
// (group g of row r stored at g^(r&7); swizzle applied to the GLOBAL source
// column so the LDS dest stays wave-uniform-base + lane*16).
// Computes acc[4][4] = A[bm:bm+128, k0:k1] * B[bn:bn+128, k0:k1]^T.
// ---------------------------------------------------------------------------
__device__ __forceinline__ void async_copy16(const __bf16* g, __bf16* l) {
    __builtin_amdgcn_global_load_lds(
        (const __attribute__((address_space(1))) void*)g,
        (__attribute__((address_space(3))) void*)l,
        16, 0, 0);
}

__device__ __forceinline__ void gemm_tile(const __bf16* __restrict__ A,
                                          const __bf16* __restrict__ B,
                                          __bf16* As, __bf16* Bs,
                                          int bm, int bn, int lda, int ldb,
                                          int k0, int k1, f32x4 acc[4][4])
{
    const int t    = threadIdx.x;
    const int lane = t & 63;
    const int wave = t >> 6;
    const int wm   = wave >> 1;
    const int wn   = wave & 1;
    const int q    = lane >> 4;
    const int ml   = lane & 15;
    const int sw   = ml & 7;

    for (int kk = k0; kk < k1; kk += 64) {
#pragma unroll
        for (int it = 0; it < 4; ++it) {
            int idx = it * 256 + t;                 // 16B-group index in [128][64] tile
            int r   = idx >> 3;
            int c   = ((idx & 7) ^ (r & 7)) << 3;   // swizzled source column
            async_copy16(A + (size_t)(bm + r) * lda + kk + c, As + idx * 8);
        }
#pragma unroll
        for (int it = 0; it < 4; ++it) {
            int idx = it * 256 + t;
            int r   = idx >> 3;
            int c   = ((idx & 7) ^ (r & 7)) << 3;
            async_copy16(B + (size_t)(bn + r) * ldb + kk + c, Bs + idx * 8);
        }
        __syncthreads();

#pragma unroll
        for (int ks = 0; ks < 64; ks += 32) {
            const int gb = ks >> 3;
            bf16x8 af[4], bfv[4];
#pragma unroll
            for (int rf = 0; rf < 4; ++rf)
                af[rf] = *(const bf16x8*)(As + (wm * 64 + rf * 16 + ml) * 64 +
                                          (((gb + q) ^ sw) << 3));
#pragma unroll
            for (int cf = 0; cf < 4; ++cf)
                bfv[cf] = *(const bf16x8*)(Bs + (wn * 64 + cf * 16 + ml) * 64 +
                                           (((gb + q) ^ sw) << 3));
#pragma unroll
            for (int rf = 0; rf < 4; ++rf)
#pragma unroll
                for (int cf = 0; cf < 4; ++cf)
                    acc[rf][cf] = __builtin_amdgcn_mfma_f32_16x16x32_bf16(
                        af[rf], bfv[cf], acc[rf][cf], 0, 0, 0);
        }
        __syncthreads();
    }
}

#define ACC_ZERO(acc)                                        \
    _Pragma("unroll") for (int _i = 0; _i < 4; ++_i)         \
    _Pragma("unroll") for (int _j = 0; _j < 4; ++_j)         \
        acc[_i][_j] = (f32x4){0.f, 0.f, 0.f, 0.f};

// C/D layout (m89-verified): col = bn + wn*64 + cf*16 + (lane&15),
//                            row = bm + wm*64 + rf*16 + (lane>>4)*4 + i

// ---------------------------------------------------------------------------
// Fused Q/K/V projection GEMMs, one dispatch of 1536 blocks.
//   bid <  512 : Q  = img  @ WQ^T  [8192 x 1024]
//   bid < 1024 : K  = text @ WK^T  [8192 x 1024]
//   else       : Vt = WV @ text^T  [1024 x 8192]   (V transposed)
// ---------------------------------------------------------------------------
__launch_bounds__(256, 4)
__global__ void qkv_kernel(const __bf16* __restrict__ imgb, const __bf16* __restrict__ textb,
                           const __bf16* __restrict__ wqb, const __bf16* __restrict__ wkb,
                           const __bf16* __restrict__ wvb,
                           __bf16* __restrict__ Qb, __bf16* __restrict__ Kb,
                           __bf16* __restrict__ Vtb)
{
    __shared__ __bf16 As[128 * 64];
    __shared__ __bf16 Bs[128 * 64];

    const int bid = blockIdx.x;
    const __bf16 *A, *B;
    __bf16* C;
    int N, bm, bn;
    if (bid < 512) {
        A = imgb;  B = wqb;   C = Qb;  N = 1024;
        bn = (bid & 7) * 128;  bm = (bid >> 3) * 128;
    } else if (bid < 1024) {
        A = textb; B = wkb;   C = Kb;  N = 1024;
        int r = bid - 512;  bn = (r & 7) * 128;  bm = (r >> 3) * 128;
    } else {
        A = wvb;   B = textb; C = Vtb; N = 8192;
        int r = bid - 1024; bn = (r & 63) * 128; bm = (r >> 6) * 128;
    }

    f32x4 acc[4][4];
    ACC_ZERO(acc);
    gemm_tile(A, B, As, Bs, bm, bn, DD, DD, 0, DD, acc);

    const int lane = threadIdx.x & 63, wave = threadIdx.x >> 6;
    const int wm = wave >> 1, wn = wave & 1, q = lane >> 4, ml = lane & 15;
#pragma unroll
    for (int rf = 0; rf < 4; ++rf)
#pragma unroll
        for (int i = 0; i < 4; ++i) {
            int row = bm + wm * 64 + rf * 16 + q * 4 + i;
#pragma unroll
            for (int cf = 0; cf < 4; ++cf) {
                int col = bn + wn * 64 + cf * 16 + ml;
                C[(size_t)row * N + col] = (__bf16)acc[rf][cf][i];
            }
        }
}

// ---------------------------------------------------------------------------
// P = exp(scale * Q @ K^T) [NI x NT] bf16, + row sums into lv (atomic).
// grid (NT/128, NI/128)
// ---------------------------------------------------------------------------
__launch_bounds__(256, 4)
__global__ void p_kernel(const __bf16* __restrict__ Qb, const __bf16* __restrict__ Kb,
                         __bf16* __restrict__ Pb, float* __restrict__ lv)
{
    __shared__ __bf16 As[128 * 64];
    __shared__ __bf16 Bs[128 * 64];

    const int bn = blockIdx.x * 128;
    const int bm = blockIdx.y * 128;

    f32x4 acc[4][4];
    ACC_ZERO(acc);
    gemm_tile(Qb, Kb, As, Bs, bm, bn, HH, HH, 0, HH, acc);

    const float scale = 0.03125f;   // 1/sqrt(1024)
    const int lane = threadIdx.x & 63, wave = threadIdx.x >> 6;
    const int wm = wave >> 1, wn = wave & 1, q = lane >> 4, ml = lane & 15;
#pragma unroll
    for (int rf = 0; rf < 4; ++rf)
#pragma unroll
        for (int i = 0; i < 4; ++i) {
            int row = bm + wm * 64 + rf * 16 + q * 4 + i;
            float s = 0.f;
#pragma unroll
            for (int cf = 0; cf < 4; ++cf) {
                int col = bn + wn * 64 + cf * 16 + ml;
                __bf16 pv = (__bf16)__expf(acc[rf][cf][i] * scale);
                Pb[(size_t)row * NT + col] = pv;
                s += (float)pv;   // sum bf16-rounded values: matches numerator
            }
            s += __shfl_xor(s, 1);
            s += __shfl_xor(s, 2);
            s += __shfl_xor(s, 4);
            s += __shfl_xor(s, 8);
            if (ml == 0) atomicAdd(lv + row, s);
        }
}

// ---------------------------------------------------------------------------
// O = (P @ Vt^T) / l -> d_out (fp32), split-K=2 via hardware f32 atomics.
// grid (NI/128, DD/128, 2): x = m-tile so the 8 n-blocks + both z sharing a
// P row-stripe have bid = m (mod 8) -> same XCD -> stripe reuse in that L2.
// d_out must be zeroed before launch.
// ---------------------------------------------------------------------------
__launch_bounds__(256, 4)
__global__ void o_kernel(const __bf16* __restrict__ Pb, const __bf16* __restrict__ Vtb,
                         const float* __restrict__ lv, float* __restrict__ out)
{
    __shared__ __bf16 As[128 * 64];
    __shared__ __bf16 Bs[128 * 64];

    const int bm = blockIdx.x * 128;
    const int bn = blockIdx.y * 128;
    const int k0 = blockIdx.z * (NT / 2);

    f32x4 acc[4][4];
    ACC_ZERO(acc);
    gemm_tile(Pb, Vtb, As, Bs, bm, bn, NT, NT, k0, k0 + NT / 2, acc);

    const int lane = threadIdx.x & 63, wave = threadIdx.x >> 6;
    const int wm = wave >> 1, wn = wave & 1, q = lane >> 4, ml = lane & 15;
#pragma unroll
    for (int rf = 0; rf < 4; ++rf)
#pragma unroll
        for (int i = 0; i < 4; ++i) {
            int row = bm + wm * 64 + rf * 16 + q * 4 + i;
            float rl = 1.0f / lv[row];
#pragma unroll
            for (int cf = 0; cf < 4; ++cf) {
                int col = bn + wn * 64 + cf * 16 + ml;
                unsafeAtomicAdd(out + (size_t)row * DD + col, acc[rf][cf][i] * rl);
            }
        }
}

// ---------------------------------------------------------------------------
extern "C" void kernel_launch(void* const* d_in, const int* in_sizes, int n_in,
                              void* d_out, int out_size, void* d_ws, size_t ws_size,
                              hipStream_t stream) {
    const float* img  = (const float*)d_in[0];
    const float* text = (const float*)d_in[1];
    const float* WQ   = (const float*)d_in[2];
    const float* WK   = (const float*)d_in[3];
    const float* WV   = (const float*)d_in[4];

    char* ws = (char*)d_ws;
    size_t off = 0;
    auto alloc = [&](size_t bytes) -> void* {
        void* p = ws + off;
        off += (bytes + 255) & ~(size_t)255;
        return p;
    };
    __bf16* imgb  = (__bf16*)alloc((size_t)NI * DD * 2);
    __bf16* textb = (__bf16*)alloc((size_t)NT * DD * 2);
    __bf16* Qb    = (__bf16*)alloc((size_t)NI * HH * 2);
    __bf16* Kb    = (__bf16*)alloc((size_t)NT * HH * 2);
    __bf16* wqb   = (__bf16*)alloc((size_t)HH * DD * 2);
    __bf16* wkb   = (__bf16*)alloc((size_t)HH * DD * 2);
    __bf16* wvb   = (__bf16*)alloc((size_t)DD * DD * 2);
    __bf16* Vtb   = (__bf16*)alloc((size_t)DD * NT * 2);
    __bf16* Pb    = (__bf16*)alloc((size_t)NI * NT * 2);   // 128 MiB
    float*  lv    = (float*)alloc((size_t)NI * 4);
    if (off > ws_size) return;

    hipMemsetAsync(lv, 0, (size_t)NI * 4, stream);
    hipMemsetAsync(d_out, 0, (size_t)NI * DD * 4, stream);

    // 1) all fp32->bf16 conversions in one dispatch
    CvtArgs ca;
    ca.src[0] = img;  ca.dst[0] = imgb;
    ca.src[1] = text; ca.dst[1] = textb;
    ca.src[2] = WQ;   ca.dst[2] = wqb;
    ca.src[3] = WK;   ca.dst[3] = wkb;
    ca.src[4] = WV;   ca.dst[4] = wvb;
    int ends[5] = {NI * DD / 1024, NT * DD / 1024, HH * DD / 1024, HH * DD / 1024, DD * DD / 1024};
    int acc_e = 0;
    for (int i = 0; i < 5; ++i) { acc_e += ends[i]; ca.blk_end[i] = acc_e; }
    cvt_all_kernel<<<dim3(acc_e), dim3(256), 0, stream>>>(ca);

    // 2) Q/K/Vt projections, one dispatch
    qkv_kernel<<<dim3(1536), dim3(256), 0, stream>>>(imgb, textb, wqb, wkb, wvb,
                                                     Qb, Kb, Vtb);
    // 3) P = exp(scale * Q K^T), rowsums
    p_kernel<<<dim3(NT / 128, NI / 128), dim3(256), 0, stream>>>(Qb, Kb, Pb, lv);
    // 4) O = (P Vt^T) / l, split-K=2, atomic into zeroed d_out
    o_kernel<<<dim3(NI / 128, DD / 128, 2), dim3(256), 0, stream>>>(Pb, Vtb, lv,
                                                                    (float*)d_out);
}